// Round 11
// baseline (208.897 us; speedup 1.0000x reference)
//
#include <hip/hip_runtime.h>

#define NB_HG 2048   // H*G = 32*64
#define DIM_N 128
#define DIM_D 128
#define DIM_S 256
#define PH 32        // staged rows per phase: 16 KB LDS -> 8 blocks/CU (wave cap)

// Numerics: golden = per-element strictly sequential ascending-d fp32 FMA over
// the SELECTED d's only (masked-out terms are exact zeros; fmaf(b,±0,acc)==acc).
// Verified bit-exact rounds 4-10. Compaction + phase split preserve order.
// LDS: Xt[cl][n ^ 4*(cl&7)] float4-XOR swizzle — SQ_LDS_BANK_CONFLICT=0
// verified rounds 5-10 (row index is phase-local cl).
// projT (d-major, in d_ws) -> 2 float4 b-loads/iter instead of 8 gathers.

__global__ void transpose_proj_kernel(const float* __restrict__ proj,
                                      float* __restrict__ projT)
{
    const int d = blockIdx.x;                      // 128
    const int s = threadIdx.x;                     // 256
    projT[d * DIM_S + s] = proj[s * DIM_D + d];    // coalesced write
}

template<bool TP>
__global__ __launch_bounds__(256)
void qjl_sketch_kernel(const float* __restrict__ data,
                       const float* __restrict__ mask,
                       const float* __restrict__ pmat,   // TP ? projT[d][s] : proj[s][d]
                       int* __restrict__ out)
{
    __shared__ float Xt[PH * DIM_N];               // 16 KB (one 32-row phase)
    __shared__ int   cidx[DIM_D];
    __shared__ int   wcnt[2];

    const int type = blockIdx.x;   // 0: inlier s<128, 1: inlier s>=128, 2: outlier s<128
    const int hg   = blockIdx.y;
    const int tid  = threadIdx.x;

    // ---------- build compacted ascending list of selected d's ----------
    bool sel = false; int pos = 0, w = 0;
    if (tid < 128) {                               // waves 0,1 only (whole waves)
        const float m = mask[hg * DIM_D + tid];    // exactly 0.0f or 1.0f
        sel = (type == 2) ? (m != 0.0f) : (m == 0.0f);
        const unsigned long long bal = __ballot(sel);
        const int lane = tid & 63;
        w = tid >> 6;
        if (lane == 0) wcnt[w] = __popcll(bal);
        pos = __popcll(bal & ((1ull << lane) - 1ull));
    }
    __syncthreads();
    if (sel) cidx[pos + (w ? wcnt[0] : 0)] = tid;  // tid == d, ascending preserved
    __syncthreads();
    const int K = wcnt[0] + wcnt[1];               // uniform across block

    const int tn = tid & 15;                       // 16 n-groups
    const int ts = tid >> 4;                       // 16 s-groups
    const int C0 = 4 * tn;
    const int s0 = ((type == 1) ? 128 : 0) + ts * 8;

    float acc[8][8];                               // [j: s-bit][i: n-slot]
    #pragma unroll
    for (int j = 0; j < 8; ++j)
        #pragma unroll
        for (int i = 0; i < 8; ++i) acc[j][i] = 0.0f;

    // staging thread mapping (constant across phases): 32 rows x 128 n
    const int cl_s = tid & 31;                     // local LDS row this thread stages
    const int nh   = tid >> 5;                     // 0..7: 16-wide n slice
    const int pcs  = 4 * (cl_s & 7);
    float* srow = &Xt[cl_s * DIM_N];

    auto STAGE = [&](int base, int kp) {
        if (cl_s < kp) {
            const int dg = cidx[base + cl_s];
            const float* Xs = data + (size_t)hg * (DIM_N * DIM_D) + dg;
            #pragma unroll
            for (int g = 0; g < 4; ++g) {
                const int n0 = nh * 16 + g * 4;    // 4-aligned logical n block
                float4 v;
                v.x = Xs[(size_t)(n0 + 0) * DIM_D];
                v.y = Xs[(size_t)(n0 + 1) * DIM_D];
                v.z = Xs[(size_t)(n0 + 2) * DIM_D];
                v.w = Xs[(size_t)(n0 + 3) * DIM_D];
                *reinterpret_cast<float4*>(&srow[n0 ^ pcs]) = v;
            }
        }
    };

    auto COMPUTE = [&](int base, int kp) {
        #pragma unroll 2
        for (int cl = 0; cl < kp; ++cl) {          // ascending selected d
            const int dg = cidx[base + cl];        // uniform LDS broadcast
            float bv[8];
            if (TP) {
                const float* pr = pmat + (size_t)dg * DIM_S + s0;
                const float4 b0 = *reinterpret_cast<const float4*>(pr);
                const float4 b1 = *reinterpret_cast<const float4*>(pr + 4);
                bv[0]=b0.x; bv[1]=b0.y; bv[2]=b0.z; bv[3]=b0.w;
                bv[4]=b1.x; bv[5]=b1.y; bv[6]=b1.z; bv[7]=b1.w;
            } else {
                #pragma unroll
                for (int j = 0; j < 8; ++j)
                    bv[j] = pmat[(size_t)(s0 + j) * DIM_D + dg];
            }

            const int P = C0 ^ (4 * (cl & 7));
            const float* r = &Xt[cl * DIM_N + P];
            const float4 q0 = *reinterpret_cast<const float4*>(r);        // n=C0..+3
            const float4 q1 = *reinterpret_cast<const float4*>(r + 64);   // n=64+C0..

            #pragma unroll
            for (int j = 0; j < 8; ++j) {
                acc[j][0] = fmaf(bv[j], q0.x, acc[j][0]);   // serial dep: order fixed
                acc[j][1] = fmaf(bv[j], q0.y, acc[j][1]);
                acc[j][2] = fmaf(bv[j], q0.z, acc[j][2]);
                acc[j][3] = fmaf(bv[j], q0.w, acc[j][3]);
                acc[j][4] = fmaf(bv[j], q1.x, acc[j][4]);
                acc[j][5] = fmaf(bv[j], q1.y, acc[j][5]);
                acc[j][6] = fmaf(bv[j], q1.z, acc[j][6]);
                acc[j][7] = fmaf(bv[j], q1.w, acc[j][7]);
            }
        }
    };

    for (int base = 0; base < K; base += PH) {     // K uniform -> no barrier divergence
        const int kp = (K - base < PH) ? (K - base) : PH;
        if (base) __syncthreads();                 // prior phase's reads done
        STAGE(base, kp);
        __syncthreads();
        COMPUTE(base, kp);
    }

    // ---------- sign-pack (bit j = s0+j > 0) and store as int32 ----------
    const size_t inl_total = (size_t)NB_HG * DIM_N * 32;   // 8388608
    #pragma unroll
    for (int i = 0; i < 8; ++i) {
        int byte = 0;
        #pragma unroll
        for (int j = 0; j < 8; ++j)
            if (acc[j][i] > 0.0f) byte |= (1 << j);
        const int n = (i < 4) ? (C0 + i) : (64 + C0 + (i - 4));
        size_t idx;
        if (type == 2)
            idx = inl_total + ((size_t)hg * DIM_N + n) * 16 + ts;
        else
            idx = ((size_t)hg * DIM_N + n) * 32 + (type == 1 ? 16 : 0) + ts;
        out[idx] = byte;
    }
}

extern "C" void kernel_launch(void* const* d_in, const int* in_sizes, int n_in,
                              void* d_out, int out_size, void* d_ws, size_t ws_size,
                              hipStream_t stream) {
    const float* data = (const float*)d_in[0];   // (1,32,64,128,128) fp32
    const float* mask = (const float*)d_in[1];   // (1,32,64,128) fp32, values {0,1}
    const float* proj = (const float*)d_in[2];   // (256,128) fp32
    int* out = (int*)d_out;                      // 8388608 inlier + 4194304 outlier int32

    dim3 grid(3, NB_HG);
    const size_t tp_bytes = (size_t)DIM_D * DIM_S * sizeof(float);   // 128 KB
    if (ws_size >= tp_bytes) {
        float* projT = (float*)d_ws;
        transpose_proj_kernel<<<DIM_D, DIM_S, 0, stream>>>(proj, projT);
        qjl_sketch_kernel<true><<<grid, 256, 0, stream>>>(data, mask, projT, out);
    } else {
        qjl_sketch_kernel<false><<<grid, 256, 0, stream>>>(data, mask, proj, out);
    }
}

// Round 12
// 186.754 us; speedup vs baseline: 1.1186x; 1.1186x over previous
//
#include <hip/hip_runtime.h>

#define NB_HG 2048   // H*G = 32*64
#define DIM_N 128
#define DIM_D 128
#define DIM_S 256
#define PH 32        // staged rows per phase
#define BSW 128      // staged B width = block's s-window

// Numerics: golden = per-element strictly sequential ascending-d fp32 FMA over
// the SELECTED d's only (masked-out terms exact zeros). Verified bit-exact
// rounds 4-11. Compaction + phase split preserve chain order; B passes through
// LDS unmodified (same bits).
// LDS swizzle family pos = idx ^ (4*(row&7)) — SQ_LDS_BANK_CONFLICT=0
// verified rounds 5-11. 4-aligned chunks: elements at p..p+3 (p = a^pcs,
// a 4-aligned) are exactly a..a+3 since pcs only touches bits 2-4.
// Inner loop: pure LDS, all offsets compile-time (unroll 8 folds cl&7),
// no cidx read, no global loads, no per-iter address VALU.

__global__ void transpose_proj_kernel(const float* __restrict__ proj,
                                      float* __restrict__ projT)
{
    const int d = blockIdx.x;                      // 128
    const int s = threadIdx.x;                     // 256
    projT[d * DIM_S + s] = proj[s * DIM_D + d];    // coalesced write
}

template<bool TP>
__global__ __launch_bounds__(256)
void qjl_sketch_kernel(const float* __restrict__ data,
                       const float* __restrict__ mask,
                       const float* __restrict__ pmat,   // TP ? projT[d][s] : proj[s][d]
                       int* __restrict__ out)
{
    __shared__ float Xt[PH * DIM_N];               // 16 KB
    __shared__ float Bs[PH * BSW];                 // 16 KB
    __shared__ int   cidx[DIM_D];
    __shared__ int   wcnt[2];

    const int type = blockIdx.x;   // 0: inlier s<128, 1: inlier s>=128, 2: outlier s<128
    const int hg   = blockIdx.y;
    const int tid  = threadIdx.x;

    // ---------- build compacted ascending list of selected d's ----------
    bool sel = false; int pos = 0, w = 0;
    if (tid < 128) {                               // waves 0,1 only (whole waves)
        const float m = mask[hg * DIM_D + tid];    // exactly 0.0f or 1.0f
        sel = (type == 2) ? (m != 0.0f) : (m == 0.0f);
        const unsigned long long bal = __ballot(sel);
        const int lane = tid & 63;
        w = tid >> 6;
        if (lane == 0) wcnt[w] = __popcll(bal);
        pos = __popcll(bal & ((1ull << lane) - 1ull));
    }
    __syncthreads();
    if (sel) cidx[pos + (w ? wcnt[0] : 0)] = tid;  // tid == d, ascending preserved
    __syncthreads();
    const int K = wcnt[0] + wcnt[1];               // uniform across block

    const int tn = tid & 15;                       // 16 n-groups
    const int ts = tid >> 4;                       // 16 s-groups
    const int C0 = 4 * tn;
    const int sl = ts * 8;                         // s_local base
    const int sbase = (type == 1) ? 128 : 0;

    float acc[8][8];                               // [j: s-bit][i: n-slot]
    #pragma unroll
    for (int j = 0; j < 8; ++j)
        #pragma unroll
        for (int i = 0; i < 8; ++i) acc[j][i] = 0.0f;

    // staging thread mapping (constant across phases)
    const int cl_s  = tid & 31;                    // LDS row this thread stages
    const int nh    = tid >> 5;                    // 0..7: 16-wide slice
    const int pcs_s = 4 * (cl_s & 7);
    float* xrow = &Xt[cl_s * DIM_N];
    float* brow = &Bs[cl_s * BSW];

    auto STAGE = [&](int base, int kp) {
        if (cl_s < kp) {
            const int dg = cidx[base + cl_s];
            const float* Xs = data + (size_t)hg * (DIM_N * DIM_D) + dg;
            #pragma unroll
            for (int g = 0; g < 4; ++g) {
                const int n0 = nh * 16 + g * 4;
                float4 v;
                v.x = Xs[(size_t)(n0 + 0) * DIM_D];
                v.y = Xs[(size_t)(n0 + 1) * DIM_D];
                v.z = Xs[(size_t)(n0 + 2) * DIM_D];
                v.w = Xs[(size_t)(n0 + 3) * DIM_D];
                *reinterpret_cast<float4*>(&xrow[n0 ^ pcs_s]) = v;
            }
            if (TP) {
                const float* Ps = pmat + (size_t)dg * DIM_S + sbase;
                #pragma unroll
                for (int g = 0; g < 4; ++g) {
                    const int s0l = nh * 16 + g * 4;
                    const float4 b = *reinterpret_cast<const float4*>(Ps + s0l);
                    *reinterpret_cast<float4*>(&brow[s0l ^ pcs_s]) = b;
                }
            } else {
                #pragma unroll
                for (int g = 0; g < 4; ++g) {
                    const int s0l = nh * 16 + g * 4;
                    float4 b;
                    b.x = pmat[(size_t)(sbase + s0l + 0) * DIM_D + dg];
                    b.y = pmat[(size_t)(sbase + s0l + 1) * DIM_D + dg];
                    b.z = pmat[(size_t)(sbase + s0l + 2) * DIM_D + dg];
                    b.w = pmat[(size_t)(sbase + s0l + 3) * DIM_D + dg];
                    *reinterpret_cast<float4*>(&brow[s0l ^ pcs_s]) = b;
                }
            }
        }
    };

    auto COMPUTE = [&](int kp) {
        #pragma unroll 8
        for (int cl = 0; cl < kp; ++cl) {          // ascending selected d
            const int pcs = 4 * (cl & 7);          // compile-time under unroll
            const int pA  = sl ^ pcs;              // holds s_local sl..sl+3
            const float4 bA = *reinterpret_cast<const float4*>(&Bs[cl * BSW + pA]);
            const float4 bB = *reinterpret_cast<const float4*>(&Bs[cl * BSW + (pA ^ 4)]);
            const int P = C0 ^ pcs;
            const float4 q0 = *reinterpret_cast<const float4*>(&Xt[cl * DIM_N + P]);
            const float4 q1 = *reinterpret_cast<const float4*>(&Xt[cl * DIM_N + P + 64]);
            const float bv[8] = {bA.x, bA.y, bA.z, bA.w, bB.x, bB.y, bB.z, bB.w};

            #pragma unroll
            for (int j = 0; j < 8; ++j) {
                acc[j][0] = fmaf(bv[j], q0.x, acc[j][0]);   // serial dep: order fixed
                acc[j][1] = fmaf(bv[j], q0.y, acc[j][1]);
                acc[j][2] = fmaf(bv[j], q0.z, acc[j][2]);
                acc[j][3] = fmaf(bv[j], q0.w, acc[j][3]);
                acc[j][4] = fmaf(bv[j], q1.x, acc[j][4]);
                acc[j][5] = fmaf(bv[j], q1.y, acc[j][5]);
                acc[j][6] = fmaf(bv[j], q1.z, acc[j][6]);
                acc[j][7] = fmaf(bv[j], q1.w, acc[j][7]);
            }
        }
    };

    for (int base = 0; base < K; base += PH) {     // K uniform -> no barrier divergence
        const int kp = (K - base < PH) ? (K - base) : PH;
        if (base) __syncthreads();                 // prior phase's reads done
        STAGE(base, kp);
        __syncthreads();
        COMPUTE(kp);
    }

    // ---------- sign-pack (bit j = sbase+sl+j > 0) and store as int32 ----------
    const size_t inl_total = (size_t)NB_HG * DIM_N * 32;   // 8388608
    #pragma unroll
    for (int i = 0; i < 8; ++i) {
        int byte = 0;
        #pragma unroll
        for (int j = 0; j < 8; ++j)
            if (acc[j][i] > 0.0f) byte |= (1 << j);
        const int n = (i < 4) ? (C0 + i) : (64 + C0 + (i - 4));
        size_t idx;
        if (type == 2)
            idx = inl_total + ((size_t)hg * DIM_N + n) * 16 + ts;
        else
            idx = ((size_t)hg * DIM_N + n) * 32 + (type == 1 ? 16 : 0) + ts;
        out[idx] = byte;
    }
}

extern "C" void kernel_launch(void* const* d_in, const int* in_sizes, int n_in,
                              void* d_out, int out_size, void* d_ws, size_t ws_size,
                              hipStream_t stream) {
    const float* data = (const float*)d_in[0];   // (1,32,64,128,128) fp32
    const float* mask = (const float*)d_in[1];   // (1,32,64,128) fp32, values {0,1}
    const float* proj = (const float*)d_in[2];   // (256,128) fp32
    int* out = (int*)d_out;                      // 8388608 inlier + 4194304 outlier int32

    dim3 grid(3, NB_HG);
    const size_t tp_bytes = (size_t)DIM_D * DIM_S * sizeof(float);   // 128 KB
    if (ws_size >= tp_bytes) {
        float* projT = (float*)d_ws;
        transpose_proj_kernel<<<DIM_D, DIM_S, 0, stream>>>(proj, projT);
        qjl_sketch_kernel<true><<<grid, 256, 0, stream>>>(data, mask, projT, out);
    } else {
        qjl_sketch_kernel<false><<<grid, 256, 0, stream>>>(data, mask, proj, out);
    }
}